// Round 5
// baseline (206.012 us; speedup 1.0000x reference)
//
#include <hip/hip_runtime.h>

#define B_ 2
#define L_ 2048
#define D_ 512
#define H_ 8
#define DK 64
#define S_ 10240
#define SCALE 0.125f

#define QSZ (4096 * 512)  // B_*L_*D_ elements

typedef _Float16 f16;
typedef __attribute__((ext_vector_type(8))) _Float16 f16x8;
typedef __attribute__((ext_vector_type(4))) float f32x4;

// ---------------------------------------------------------------------------
// split x (fp32) -> xh + xl (f16 hi/lo)
// ---------------------------------------------------------------------------
__global__ __launch_bounds__(256) void split_x_kernel(
    const float* __restrict__ x, f16* __restrict__ xh, f16* __restrict__ xl)
{
    const size_t i0 = ((size_t)blockIdx.x * 256 + threadIdx.x) * 8;
    const float4 a = *(const float4*)&x[i0];
    const float4 b = *(const float4*)&x[i0 + 4];
    const float vals[8] = {a.x, a.y, a.z, a.w, b.x, b.y, b.z, b.w};
    union { f16 h[8]; uint4 u; } H, Lo;
#pragma unroll
    for (int j = 0; j < 8; j++) {
        const f16 hh = (f16)vals[j];
        H.h[j] = hh;
        Lo.h[j] = (f16)(vals[j] - (float)hh);
    }
    *(uint4*)&xh[i0] = H.u;
    *(uint4*)&xl[i0] = Lo.u;
}

// ---------------------------------------------------------------------------
// split Wq,Wk -> concat wh/wl [1024][512] f16 hi/lo; biascat[1024] = bq|bk
// ---------------------------------------------------------------------------
__global__ __launch_bounds__(256) void split_w_kernel(
    const float* __restrict__ Wq, const float* __restrict__ Wk,
    const float* __restrict__ bq, const float* __restrict__ bk,
    f16* __restrict__ wh, f16* __restrict__ wl, float* __restrict__ biascat)
{
    const size_t i0 = ((size_t)blockIdx.x * 256 + threadIdx.x) * 8;
    const float* src = (i0 < (size_t)512 * 512) ? Wq + i0 : Wk + (i0 - (size_t)512 * 512);
    const float4 a = *(const float4*)&src[0];
    const float4 b = *(const float4*)&src[4];
    const float vals[8] = {a.x, a.y, a.z, a.w, b.x, b.y, b.z, b.w};
    union { f16 h[8]; uint4 u; } H, Lo;
#pragma unroll
    for (int j = 0; j < 8; j++) {
        const f16 hh = (f16)vals[j];
        H.h[j] = hh;
        Lo.h[j] = (f16)(vals[j] - (float)hh);
    }
    *(uint4*)&wh[i0] = H.u;
    *(uint4*)&wl[i0] = Lo.u;
    if (blockIdx.x == 0)
        for (int e = threadIdx.x; e < 1024; e += 256)
            biascat[e] = (e < 512) ? bq[e] : bk[e - 512];
}

// ---------------------------------------------------------------------------
// q,k projections via split-f16 MFMA GEMM: [4096 x 512] . [512 x 1024]^T
// ---------------------------------------------------------------------------
__global__ __launch_bounds__(256) void projqk_kernel(
    const f16* __restrict__ xh, const f16* __restrict__ xl,
    const f16* __restrict__ wh, const f16* __restrict__ wl,
    const float* __restrict__ biascat,
    f16* __restrict__ qh, f16* __restrict__ ql,
    f16* __restrict__ kh, f16* __restrict__ kl)
{
    const int n0 = blockIdx.x * 128;   // rows (tokens)
    const int e0 = blockIdx.y * 128;   // cols (proj dims, 0..1023)
    const int t = threadIdx.x;

    __shared__ __align__(16) f16 lds[4 * 128 * 64];   // 64 KB
    f16* ash = lds;
    f16* asl = lds + 8192;
    f16* bsh = lds + 16384;
    f16* bsl = lds + 24576;

    const int lane = t & 63, wid = t >> 6;
    const int wr = wid >> 1, wc = wid & 1;
    const int lrow = lane & 15, lk = lane >> 4;

    f32x4 acc[4][4];
#pragma unroll
    for (int i = 0; i < 4; i++)
#pragma unroll
        for (int j = 0; j < 4; j++)
#pragma unroll
            for (int r = 0; r < 4; r++) acc[i][j][r] = 0.f;

    for (int kt = 0; kt < 8; kt++) {
        __syncthreads();
#pragma unroll
        for (int i = 0; i < 4; i++) {
            const int g = i * 256 + t;
            const int row = g >> 3, c = g & 7;
            const int cs = c ^ (row & 7);
            const int lo = row * 64 + cs * 8;
            const size_t ga = (size_t)(n0 + row) * 512 + kt * 64 + c * 8;
            const size_t gb = (size_t)(e0 + row) * 512 + kt * 64 + c * 8;
            *(uint4*)&ash[lo] = *(const uint4*)&xh[ga];
            *(uint4*)&asl[lo] = *(const uint4*)&xl[ga];
            *(uint4*)&bsh[lo] = *(const uint4*)&wh[gb];
            *(uint4*)&bsl[lo] = *(const uint4*)&wl[gb];
        }
        __syncthreads();

#pragma unroll
        for (int kk = 0; kk < 2; kk++) {
            f16x8 ah[4], al[4], bh_[4], bl_[4];
#pragma unroll
            for (int lt = 0; lt < 4; lt++) {
                const int row = wr * 64 + lt * 16 + lrow;
                const int cs = (kk * 4 + lk) ^ (row & 7);
                const int o = row * 64 + cs * 8;
                ah[lt] = *(const f16x8*)&ash[o];
                al[lt] = *(const f16x8*)&asl[o];
            }
#pragma unroll
            for (int jt = 0; jt < 4; jt++) {
                const int row = wc * 64 + jt * 16 + lrow;
                const int cs = (kk * 4 + lk) ^ (row & 7);
                const int o = row * 64 + cs * 8;
                bh_[jt] = *(const f16x8*)&bsh[o];
                bl_[jt] = *(const f16x8*)&bsl[o];
            }
#pragma unroll
            for (int lt = 0; lt < 4; lt++)
#pragma unroll
                for (int jt = 0; jt < 4; jt++) {
                    acc[lt][jt] = __builtin_amdgcn_mfma_f32_16x16x32_f16(
                        ah[lt], bh_[jt], acc[lt][jt], 0, 0, 0);
                    acc[lt][jt] = __builtin_amdgcn_mfma_f32_16x16x32_f16(
                        ah[lt], bl_[jt], acc[lt][jt], 0, 0, 0);
                    acc[lt][jt] = __builtin_amdgcn_mfma_f32_16x16x32_f16(
                        al[lt], bh_[jt], acc[lt][jt], 0, 0, 0);
                }
        }
    }

    // Epilogue: bias add, split to hi/lo, LDS transpose for coalesced stores.
    const int PSTR = 72;
    f16* tile = lds + wid * 64 * PSTR;
    const int ebase = e0 + wc * 64;
    const bool isQ = (blockIdx.y < 4);
    const int colbase = (blockIdx.y & 3) * 128;

#pragma unroll
    for (int round = 0; round < 2; round++) {
        __syncthreads();
#pragma unroll
        for (int jt = 0; jt < 4; jt++) {
            const float bval = biascat[ebase + jt * 16 + lrow];
#pragma unroll
            for (int lt = 0; lt < 4; lt++)
#pragma unroll
                for (int r = 0; r < 4; r++) {
                    const float y = acc[lt][jt][r] + bval;
                    const f16 hi = (f16)y;
                    const f16 val = (round == 0) ? hi : (f16)(y - (float)hi);
                    tile[(lt * 16 + lk * 4 + r) * PSTR + jt * 16 + lrow] = val;
                }
        }
        __syncthreads();
        f16* dst = isQ ? ((round == 0) ? qh : ql) : ((round == 0) ? kh : kl);
        for (int i = t; i < 2048; i += 256) {
            const int w = i >> 9, rem = i & 511, row = rem >> 3, c = rem & 7;
            const int n = n0 + (w >> 1) * 64 + row;
            const int col = colbase + (w & 1) * 64 + c * 8;
            *(uint4*)&dst[(size_t)n * 512 + col] =
                *(const uint4*)&lds[w * 64 * PSTR + row * PSTR + c * 8];
        }
    }
}

// ---------------------------------------------------------------------------
__global__ void hist_kernel(const int* __restrict__ samp, int* __restrict__ counts)
{
    const int i = blockIdx.x * 256 + threadIdx.x;
    if (i < S_) atomicAdd(&counts[samp[i]], 1);
}

// ---------------------------------------------------------------------------
__global__ __launch_bounds__(256) void kbar_part_kernel(
    const f16* __restrict__ kh, const f16* __restrict__ kl,
    const int* __restrict__ counts, float* __restrict__ kbar_part)
{
    const int bh = blockIdx.x, c = blockIdx.y;
    const int b = bh >> 3, h = bh & 7;
    const int j0 = c * 256;
    const int t = threadIdx.x;
    const int e = t & 63, jg = t >> 6;
    const f16* kbh = kh + (size_t)b * L_ * D_ + h * DK + e;
    const f16* kbl = kl + (size_t)b * L_ * D_ + h * DK + e;
    float s = 0.f;
    for (int j = j0 + jg; j < j0 + 256; j += 4) {
        const float kv = (float)kbh[(size_t)j * D_] + (float)kbl[(size_t)j * D_];
        s += (float)counts[j] * kv;
    }
    __shared__ float red[4][64];
    red[jg][e] = s;
    __syncthreads();
    if (t < 64)
        kbar_part[(size_t)(bh * 8 + c) * 64 + t] =
            red[0][t] + red[1][t] + red[2][t] + red[3][t];
}

// ---------------------------------------------------------------------------
__global__ void kbar_combine_kernel(const float* __restrict__ kbar_part,
                                    float* __restrict__ kbar)
{
    const int bh = blockIdx.x;
    const int t = threadIdx.x;   // 64
    float s = 0.f;
#pragma unroll
    for (int p = 0; p < 8; p++) s += kbar_part[(size_t)(bh * 8 + p) * 64 + t];
    kbar[bh * 64 + t] = s * (1.0f / (float)S_);
}

// ---------------------------------------------------------------------------
// mstat: per (l-chunk128, bh) block. q frags in registers, K double-buffered
// in LDS, loop over all 16 j-tiles.  Fused: masked row-max (split-f16 MFMA),
// q.kbar dot, and block-level argmax of (max - dot).
// ---------------------------------------------------------------------------
__global__ __launch_bounds__(256) void mstat_kernel(
    const f16* __restrict__ qh, const f16* __restrict__ ql,
    const f16* __restrict__ kh, const f16* __restrict__ kl,
    const int* __restrict__ counts, const float* __restrict__ kbar,
    float* __restrict__ bestv, int* __restrict__ besti)
{
    // XCD swizzle: 8 XCDs, 32 blocks each; XCD x handles bh {2x, 2x+1}
    const int id = blockIdx.x;
    const int xcd = id & 7, seq = id >> 3;
    const int bh = xcd * 2 + (seq >> 4);
    const int lt16 = seq & 15;
    const int b = bh >> 3, h = bh & 7;
    const int l0 = lt16 * 128;
    const int t = threadIdx.x;
    const int lane = t & 63, wid = t >> 6;
    const int wr = wid >> 1, wc = wid & 1;
    const int lrow = lane & 15, lk = lane >> 4;

    __shared__ __align__(16) f16 kbuf[2][2][128 * 64];  // [dbuf][hi/lo]  64 KB
    __shared__ float kbar_lds[64];
    __shared__ float dot_lds[128];
    __shared__ float wv_[4];
    __shared__ int wi_[4];

    // q fragments in registers (loaded once)
    f16x8 qa_h[2][4], qa_l[2][4];
    {
        const size_t qrowbase = (size_t)(b * L_ + l0 + wr * 64) * D_ + h * DK;
#pragma unroll
        for (int kk = 0; kk < 2; kk++)
#pragma unroll
            for (int lt = 0; lt < 4; lt++) {
                const size_t o = qrowbase + (size_t)(lt * 16 + lrow) * D_ + kk * 32 + lk * 8;
                qa_h[kk][lt] = *(const f16x8*)&qh[o];
                qa_l[kk][lt] = *(const f16x8*)&ql[o];
            }
    }
    if (t < 64) kbar_lds[t] = kbar[bh * 64 + t];

    const f16* khb = kh + (size_t)b * L_ * D_ + h * DK;
    const f16* klb = kl + (size_t)b * L_ * D_ + h * DK;

    const int srow = t >> 3, sc = t & 7;          // wait: need 4 chunks/thread
    (void)srow; (void)sc;

    uint4 rh[4], rl[4];
    // prologue: stage tile 0
#pragma unroll
    for (int i = 0; i < 4; i++) {
        const int g = i * 256 + t, row = g >> 3, c = g & 7;
        const size_t go = (size_t)row * D_ + c * 8;
        rh[i] = *(const uint4*)&khb[go];
        rl[i] = *(const uint4*)&klb[go];
    }
#pragma unroll
    for (int i = 0; i < 4; i++) {
        const int g = i * 256 + t, row = g >> 3, c = g & 7;
        const int cs = c ^ (row & 7);
        *(uint4*)&kbuf[0][0][row * 64 + cs * 8] = rh[i];
        *(uint4*)&kbuf[0][1][row * 64 + cs * 8] = rl[i];
    }
    __syncthreads();

    float rmax[4][4];
#pragma unroll
    for (int lt = 0; lt < 4; lt++)
#pragma unroll
        for (int r = 0; r < 4; r++) rmax[lt][r] = -3.9e38f;

    int cur = 0;
    for (int jt = 0; jt < 16; jt++) {
        // issue next-tile global loads (latency hides under MFMA)
        if (jt < 15) {
            const size_t kbase = (size_t)((jt + 1) * 128) * D_;
#pragma unroll
            for (int i = 0; i < 4; i++) {
                const int g = i * 256 + t, row = g >> 3, c = g & 7;
                const size_t go = kbase + (size_t)row * D_ + c * 8;
                rh[i] = *(const uint4*)&khb[go];
                rl[i] = *(const uint4*)&klb[go];
            }
        }

        f32x4 acc[4][4];
#pragma unroll
        for (int i = 0; i < 4; i++)
#pragma unroll
            for (int j = 0; j < 4; j++)
#pragma unroll
                for (int r = 0; r < 4; r++) acc[i][j][r] = 0.f;

#pragma unroll
        for (int kk = 0; kk < 2; kk++) {
            f16x8 bhf[4], blf[4];
#pragma unroll
            for (int jtt = 0; jtt < 4; jtt++) {
                const int row = wc * 64 + jtt * 16 + lrow;
                const int cs = (kk * 4 + lk) ^ (row & 7);
                const int o = row * 64 + cs * 8;
                bhf[jtt] = *(const f16x8*)&kbuf[cur][0][o];
                blf[jtt] = *(const f16x8*)&kbuf[cur][1][o];
            }
#pragma unroll
            for (int lt = 0; lt < 4; lt++)
#pragma unroll
                for (int jtt = 0; jtt < 4; jtt++) {
                    acc[lt][jtt] = __builtin_amdgcn_mfma_f32_16x16x32_f16(
                        qa_h[kk][lt], bhf[jtt], acc[lt][jtt], 0, 0, 0);
                    acc[lt][jtt] = __builtin_amdgcn_mfma_f32_16x16x32_f16(
                        qa_h[kk][lt], blf[jtt], acc[lt][jtt], 0, 0, 0);
                    acc[lt][jtt] = __builtin_amdgcn_mfma_f32_16x16x32_f16(
                        qa_l[kk][lt], bhf[jtt], acc[lt][jtt], 0, 0, 0);
                }
        }

        // masked max
#pragma unroll
        for (int jtt = 0; jtt < 4; jtt++) {
            const int cj = jt * 128 + wc * 64 + jtt * 16 + lrow;
            const float addend = (counts[cj] > 0) ? 0.f : -3.0e38f;
#pragma unroll
            for (int lt = 0; lt < 4; lt++)
#pragma unroll
                for (int r = 0; r < 4; r++)
                    rmax[lt][r] = fmaxf(rmax[lt][r], acc[lt][jtt][r] + addend);
        }

        __syncthreads();
        if (jt < 15) {
#pragma unroll
            for (int i = 0; i < 4; i++) {
                const int g = i * 256 + t, row = g >> 3, c = g & 7;
                const int cs = c ^ (row & 7);
                *(uint4*)&kbuf[cur ^ 1][0][row * 64 + cs * 8] = rh[i];
                *(uint4*)&kbuf[cur ^ 1][1][row * 64 + cs * 8] = rl[i];
            }
        }
        __syncthreads();
        cur ^= 1;
    }

    // reduce row-max across the 16 column-lanes
#pragma unroll
    for (int m = 1; m < 16; m <<= 1)
#pragma unroll
        for (int lt = 0; lt < 4; lt++)
#pragma unroll
            for (int r = 0; r < 4; r++)
                rmax[lt][r] = fmaxf(rmax[lt][r], __shfl_xor(rmax[lt][r], m));

    // q.kbar dot from registers: lane holds chunks (kk, lk) of row lt*16+lrow
    {
        float dlt[4];
#pragma unroll
        for (int lt = 0; lt < 4; lt++) {
            float d = 0.f;
#pragma unroll
            for (int kk = 0; kk < 2; kk++) {
                const f16x8 hv = qa_h[kk][lt];
                const f16x8 lv = qa_l[kk][lt];
#pragma unroll
                for (int i = 0; i < 8; i++)
                    d += ((float)hv[i] + (float)lv[i]) * kbar_lds[kk * 32 + lk * 8 + i];
            }
            dlt[lt] = d;
        }
#pragma unroll
        for (int lt = 0; lt < 4; lt++) {
            dlt[lt] += __shfl_xor(dlt[lt], 16);
            dlt[lt] += __shfl_xor(dlt[lt], 32);
        }
        if (lane < 16) {
#pragma unroll
            for (int lt = 0; lt < 4; lt++)
                dot_lds[wr * 64 + lt * 16 + lane] = dlt[lt];
        }
    }
    __syncthreads();

    // block argmax of (rmax - dot)
    float bv_ = -3.9e38f;
    int bi_ = 0x7fffffff;
#pragma unroll
    for (int lt = 0; lt < 4; lt++)
#pragma unroll
        for (int r = 0; r < 4; r++) {
            const int rl_ = wr * 64 + lt * 16 + lk * 4 + r;
            const float val = rmax[lt][r] - dot_lds[rl_];
            const int idx = l0 + rl_;
            if (val > bv_ || (val == bv_ && idx < bi_)) { bv_ = val; bi_ = idx; }
        }
#pragma unroll
    for (int m = 1; m < 64; m <<= 1) {
        const float ov = __shfl_xor(bv_, m);
        const int oi = __shfl_xor(bi_, m);
        if (ov > bv_ || (ov == bv_ && oi < bi_)) { bv_ = ov; bi_ = oi; }
    }
    if (lane == 0) { wv_[wid] = bv_; wi_[wid] = bi_; }
    __syncthreads();
    if (t == 0) {
        float fb = wv_[0]; int fi = wi_[0];
#pragma unroll
        for (int w = 1; w < 4; w++) {
            if (wv_[w] > fb || (wv_[w] == fb && wi_[w] < fi)) { fb = wv_[w]; fi = wi_[w]; }
        }
        bestv[bh * 16 + lt16] = fb;
        besti[bh * 16 + lt16] = fi;
    }
}

// ---------------------------------------------------------------------------
// final argmax: 16 chunks ascending, strict > keeps first occurrence
// ---------------------------------------------------------------------------
__global__ void argmax2_kernel(const float* __restrict__ bestv,
                               const int* __restrict__ besti, int* __restrict__ U)
{
    const int t = threadIdx.x;
    if (t < 16) {
        float best = -3.9e38f;
        int bi = 0;
#pragma unroll
        for (int c = 0; c < 16; c++) {
            const float v = bestv[t * 16 + c];
            const int oi = besti[t * 16 + c];
            if (v > best || (v == best && oi < bi)) { best = v; bi = oi; }
        }
        U[t] = bi;
    }
}

// ---------------------------------------------------------------------------
// ctx stage 1: scores from kh/kl . q_u, softmax partials, x-weighted partial
// ---------------------------------------------------------------------------
__global__ __launch_bounds__(256) void ctx_part_kernel(
    const f16* __restrict__ qh, const f16* __restrict__ ql,
    const f16* __restrict__ kh, const f16* __restrict__ kl,
    const float* __restrict__ x, const int* __restrict__ U,
    float* __restrict__ xbar_part, float* __restrict__ cm, float* __restrict__ cs)
{
    const int bh = blockIdx.x, c = blockIdx.y;   // 16 x 16
    const int b = bh >> 3, h = bh & 7;
    const int l0 = c * 128;
    const int t = threadIdx.x;

    __shared__ float qr[64];
    __shared__ float w[128];
    __shared__ float red[128];

    const int u = U[bh];
    if (t < 64)
        qr[t] = (float)qh[(size_t)(b * L_ + u) * D_ + h * DK + t] +
                (float)ql[(size_t)(b * L_ + u) * D_ + h * DK + t];
    __syncthreads();

    {
        const int row = t >> 1, half = t & 1;
        const size_t off = (size_t)(b * L_ + l0 + row) * D_ + h * DK + half * 32;
        const f16* krh = kh + off;
        const f16* krl = kl + off;
        float dot = 0.f;
#pragma unroll
        for (int cc = 0; cc < 4; cc++) {
            const f16x8 hv = *(const f16x8*)&krh[cc * 8];
            const f16x8 lv = *(const f16x8*)&krl[cc * 8];
#pragma unroll
            for (int i = 0; i < 8; i++)
                dot += ((float)hv[i] + (float)lv[i]) * qr[half * 32 + cc * 8 + i];
        }
        dot += __shfl_xor(dot, 1);
        if (half == 0) w[row] = dot * SCALE;
    }
    __syncthreads();

    if (t < 128) red[t] = w[t];
    __syncthreads();
    for (int s = 64; s > 0; s >>= 1) {
        if (t < s) red[t] = fmaxf(red[t], red[t + s]);
        __syncthreads();
    }
    const float m = red[0];
    __syncthreads();

    if (t < 128) { const float e = expf(w[t] - m); w[t] = e; red[t] = e; }
    __syncthreads();
    for (int s = 64; s > 0; s >>= 1) {
        if (t < s) red[t] += red[t + s];
        __syncthreads();
    }
    const float ssum = red[0];

    float ax = 0.f, ay = 0.f;
    const float* xb = x + (size_t)(b * L_ + l0) * D_ + t * 2;
#pragma unroll 4
    for (int l = 0; l < 128; l++) {
        const float wl = w[l];
        const float2 xv = *(const float2*)(xb + (size_t)l * D_);
        ax = fmaf(wl, xv.x, ax);
        ay = fmaf(wl, xv.y, ay);
    }
    float2 st; st.x = ax; st.y = ay;
    *(float2*)&xbar_part[(size_t)(bh * 16 + c) * 512 + t * 2] = st;
    if (t == 0) { cm[bh * 16 + c] = m; cs[bh * 16 + c] = ssum; }
}

// ---------------------------------------------------------------------------
__global__ __launch_bounds__(256) void ctx_combine_kernel(
    const float* __restrict__ xbar_part, const float* __restrict__ cm,
    const float* __restrict__ cs, const float* __restrict__ Wv,
    const float* __restrict__ bv, float* __restrict__ ctx)
{
    const int bh = blockIdx.x;
    const int h = bh & 7;
    const int t = threadIdx.x;
    __shared__ float xbar[512];

    float M = -3.9e38f;
#pragma unroll
    for (int c = 0; c < 16; c++) M = fmaxf(M, cm[bh * 16 + c]);
    float denom = 0.f;
    float ax = 0.f, ay = 0.f;
#pragma unroll
    for (int c = 0; c < 16; c++) {
        const float f = expf(cm[bh * 16 + c] - M);
        denom += f * cs[bh * 16 + c];
        const float2 p = *(const float2*)&xbar_part[(size_t)(bh * 16 + c) * 512 + t * 2];
        ax = fmaf(f, p.x, ax);
        ay = fmaf(f, p.y, ay);
    }
    xbar[t * 2] = ax; xbar[t * 2 + 1] = ay;
    __syncthreads();

    if (t < 64) {
        const float* wr = Wv + (size_t)(h * 64 + t) * D_;
        float acc = 0.f;
#pragma unroll 8
        for (int d = 0; d < 128; d++) {
            const float4 wv4 = *(const float4*)&wr[d * 4];
            acc += wv4.x * xbar[d * 4] + wv4.y * xbar[d * 4 + 1] +
                   wv4.z * xbar[d * 4 + 2] + wv4.w * xbar[d * 4 + 3];
        }
        ctx[bh * 64 + t] = acc / denom + bv[h * 64 + t];
    }
}

// ---------------------------------------------------------------------------
// compute the 2 distinct output rows once
// ---------------------------------------------------------------------------
__global__ __launch_bounds__(256) void out_row_kernel(
    const float* __restrict__ ctx, const float* __restrict__ Wo,
    const float* __restrict__ bo, float* __restrict__ rowbuf)
{
    const int b = blockIdx.x;
    const int t = threadIdx.x;
    __shared__ float cb[512];
    cb[t] = ctx[b * 512 + t];
    cb[t + 256] = ctx[b * 512 + 256 + t];
    __syncthreads();
#pragma unroll
    for (int r = 0; r < 2; r++) {
        const int e = t + r * 256;
        const float* wr = Wo + (size_t)e * D_;
        float acc = 0.f;
#pragma unroll 8
        for (int c = 0; c < 128; c++) {
            const float4 wv = *(const float4*)(wr + c * 4);
            acc += wv.x * cb[c * 4] + wv.y * cb[c * 4 + 1] +
                   wv.z * cb[c * 4 + 2] + wv.w * cb[c * 4 + 3];
        }
        rowbuf[b * 512 + e] = acc + bo[e];
    }
}

// ---------------------------------------------------------------------------
// broadcast the row to all L positions (pure write bandwidth)
// ---------------------------------------------------------------------------
__global__ __launch_bounds__(256) void out_bcast_kernel(
    const float* __restrict__ rowbuf, float* __restrict__ out)
{
    const int g = blockIdx.x * 256 + threadIdx.x;   // float4 index, 524288 total
    const int l = g >> 7, c = g & 127;
    const int b = l >> 11;
    ((float4*)out)[g] = ((const float4*)rowbuf)[b * 128 + c];
}

// ---------------------------------------------------------------------------
extern "C" void kernel_launch(void* const* d_in, const int* in_sizes, int n_in,
                              void* d_out, int out_size, void* d_ws, size_t ws_size,
                              hipStream_t stream)
{
    const float* x   = (const float*)d_in[0];
    const int* samp  = (const int*)d_in[1];
    const float* Wq  = (const float*)d_in[2];
    const float* bq  = (const float*)d_in[3];
    const float* Wk  = (const float*)d_in[4];
    const float* bk  = (const float*)d_in[5];
    const float* Wv  = (const float*)d_in[6];
    const float* bv  = (const float*)d_in[7];
    const float* Wo  = (const float*)d_in[8];
    const float* bo  = (const float*)d_in[9];
    float* out = (float*)d_out;

    f16* qh = (f16*)d_ws;
    f16* ql = qh + QSZ;
    f16* kh = ql + QSZ;
    f16* kl = kh + QSZ;
    f16* xh = kl + QSZ;
    f16* xl = xh + QSZ;
    f16* wh = xl + QSZ;                       // 1024*512
    f16* wl = wh + 1024 * 512;
    float* fbase     = (float*)(wl + 1024 * 512);
    float* biascat   = fbase;                 // 1024
    float* kbar_part = biascat + 1024;        // 8192
    float* kbar      = kbar_part + 8192;      // 1024
    float* xbar_part = kbar + 1024;           // 131072
    float* cm        = xbar_part + 131072;    // 256
    float* cs        = cm + 256;              // 256
    float* bestv     = cs + 256;              // 256
    float* ctx       = bestv + 256;           // 1024
    float* rowbuf    = ctx + 1024;            // 1024
    int* counts      = (int*)(rowbuf + 1024); // 2048
    int* besti       = counts + 2048;         // 256
    int* U           = besti + 256;           // 16

    hipMemsetAsync(counts, 0, 2048 * sizeof(int), stream);
    split_x_kernel<<<1024, 256, 0, stream>>>(x, xh, xl);
    split_w_kernel<<<256, 256, 0, stream>>>(Wq, Wk, bq, bk, wh, wl, biascat);
    projqk_kernel<<<dim3(32, 8), 256, 0, stream>>>(xh, xl, wh, wl, biascat,
                                                   qh, ql, kh, kl);
    hist_kernel<<<40, 256, 0, stream>>>(samp, counts);
    kbar_part_kernel<<<dim3(16, 8), 256, 0, stream>>>(kh, kl, counts, kbar_part);
    kbar_combine_kernel<<<16, 64, 0, stream>>>(kbar_part, kbar);
    mstat_kernel<<<256, 256, 0, stream>>>(qh, ql, kh, kl, counts, kbar, bestv, besti);
    argmax2_kernel<<<1, 64, 0, stream>>>(bestv, besti, U);
    ctx_part_kernel<<<dim3(16, 16), 256, 0, stream>>>(qh, ql, kh, kl, x, U,
                                                      xbar_part, cm, cs);
    ctx_combine_kernel<<<16, 256, 0, stream>>>(xbar_part, cm, cs, Wv, bv, ctx);
    out_row_kernel<<<2, 256, 0, stream>>>(ctx, Wo, bo, rowbuf);
    out_bcast_kernel<<<2048, 256, 0, stream>>>(rowbuf, out);
}

// Round 6
// 181.206 us; speedup vs baseline: 1.1369x; 1.1369x over previous
//
#include <hip/hip_runtime.h>

#define B_ 2
#define L_ 2048
#define D_ 512
#define H_ 8
#define DK 64
#define S_ 10240
#define SCALE 0.125f

#define QSZ (4096 * 512)  // B_*L_*D_ elements

typedef _Float16 f16;
typedef __attribute__((ext_vector_type(8))) _Float16 f16x8;
typedef __attribute__((ext_vector_type(4))) float f32x4;

// ---------------------------------------------------------------------------
// prep: split x -> xh/xl, split Wq|Wk -> wh/wl + biascat, histogram of samp
// ---------------------------------------------------------------------------
__global__ __launch_bounds__(256) void prep_kernel(
    const float* __restrict__ x,
    const float* __restrict__ Wq, const float* __restrict__ Wk,
    const float* __restrict__ bq, const float* __restrict__ bk,
    const int* __restrict__ samp,
    f16* __restrict__ xh, f16* __restrict__ xl,
    f16* __restrict__ wh, f16* __restrict__ wl,
    float* __restrict__ biascat, int* __restrict__ counts)
{
    const int bid = blockIdx.x;
    const int t = threadIdx.x;
    if (bid < 1024) {
        const size_t i0 = ((size_t)bid * 256 + t) * 8;
        const float4 a = *(const float4*)&x[i0];
        const float4 b = *(const float4*)&x[i0 + 4];
        const float vals[8] = {a.x, a.y, a.z, a.w, b.x, b.y, b.z, b.w};
        union { f16 h[8]; uint4 u; } H, Lo;
#pragma unroll
        for (int j = 0; j < 8; j++) {
            const f16 hh = (f16)vals[j];
            H.h[j] = hh;
            Lo.h[j] = (f16)(vals[j] - (float)hh);
        }
        *(uint4*)&xh[i0] = H.u;
        *(uint4*)&xl[i0] = Lo.u;
    } else if (bid < 1280) {
        const size_t i0 = ((size_t)(bid - 1024) * 256 + t) * 8;
        const float* src = (i0 < (size_t)512 * 512) ? Wq + i0
                                                    : Wk + (i0 - (size_t)512 * 512);
        const float4 a = *(const float4*)&src[0];
        const float4 b = *(const float4*)&src[4];
        const float vals[8] = {a.x, a.y, a.z, a.w, b.x, b.y, b.z, b.w};
        union { f16 h[8]; uint4 u; } H, Lo;
#pragma unroll
        for (int j = 0; j < 8; j++) {
            const f16 hh = (f16)vals[j];
            H.h[j] = hh;
            Lo.h[j] = (f16)(vals[j] - (float)hh);
        }
        *(uint4*)&wh[i0] = H.u;
        *(uint4*)&wl[i0] = Lo.u;
        if (bid == 1024)
            for (int e = t; e < 1024; e += 256)
                biascat[e] = (e < 512) ? bq[e] : bk[e - 512];
    } else {
        const int i = (bid - 1280) * 256 + t;
        if (i < S_) atomicAdd(&counts[samp[i]], 1);
    }
}

// ---------------------------------------------------------------------------
// q,k projections via split-f16 MFMA GEMM: [4096 x 512] . [512 x 1024]^T
// ---------------------------------------------------------------------------
__global__ __launch_bounds__(256) void projqk_kernel(
    const f16* __restrict__ xh, const f16* __restrict__ xl,
    const f16* __restrict__ wh, const f16* __restrict__ wl,
    const float* __restrict__ biascat,
    f16* __restrict__ qh, f16* __restrict__ ql,
    f16* __restrict__ kh, f16* __restrict__ kl)
{
    const int n0 = blockIdx.x * 128;   // rows (tokens)
    const int e0 = blockIdx.y * 128;   // cols (proj dims, 0..1023)
    const int t = threadIdx.x;

    __shared__ __align__(16) f16 lds[4 * 128 * 64];   // 64 KB
    f16* ash = lds;
    f16* asl = lds + 8192;
    f16* bsh = lds + 16384;
    f16* bsl = lds + 24576;

    const int lane = t & 63, wid = t >> 6;
    const int wr = wid >> 1, wc = wid & 1;
    const int lrow = lane & 15, lk = lane >> 4;

    f32x4 acc[4][4];
#pragma unroll
    for (int i = 0; i < 4; i++)
#pragma unroll
        for (int j = 0; j < 4; j++)
#pragma unroll
            for (int r = 0; r < 4; r++) acc[i][j][r] = 0.f;

    for (int kt = 0; kt < 8; kt++) {
        __syncthreads();
#pragma unroll
        for (int i = 0; i < 4; i++) {
            const int g = i * 256 + t;
            const int row = g >> 3, c = g & 7;
            const int cs = c ^ (row & 7);
            const int lo = row * 64 + cs * 8;
            const size_t ga = (size_t)(n0 + row) * 512 + kt * 64 + c * 8;
            const size_t gb = (size_t)(e0 + row) * 512 + kt * 64 + c * 8;
            *(uint4*)&ash[lo] = *(const uint4*)&xh[ga];
            *(uint4*)&asl[lo] = *(const uint4*)&xl[ga];
            *(uint4*)&bsh[lo] = *(const uint4*)&wh[gb];
            *(uint4*)&bsl[lo] = *(const uint4*)&wl[gb];
        }
        __syncthreads();

#pragma unroll
        for (int kk = 0; kk < 2; kk++) {
            f16x8 ah[4], al[4], bh_[4], bl_[4];
#pragma unroll
            for (int lt = 0; lt < 4; lt++) {
                const int row = wr * 64 + lt * 16 + lrow;
                const int cs = (kk * 4 + lk) ^ (row & 7);
                const int o = row * 64 + cs * 8;
                ah[lt] = *(const f16x8*)&ash[o];
                al[lt] = *(const f16x8*)&asl[o];
            }
#pragma unroll
            for (int jt = 0; jt < 4; jt++) {
                const int row = wc * 64 + jt * 16 + lrow;
                const int cs = (kk * 4 + lk) ^ (row & 7);
                const int o = row * 64 + cs * 8;
                bh_[jt] = *(const f16x8*)&bsh[o];
                bl_[jt] = *(const f16x8*)&bsl[o];
            }
#pragma unroll
            for (int lt = 0; lt < 4; lt++)
#pragma unroll
                for (int jt = 0; jt < 4; jt++) {
                    acc[lt][jt] = __builtin_amdgcn_mfma_f32_16x16x32_f16(
                        ah[lt], bh_[jt], acc[lt][jt], 0, 0, 0);
                    acc[lt][jt] = __builtin_amdgcn_mfma_f32_16x16x32_f16(
                        ah[lt], bl_[jt], acc[lt][jt], 0, 0, 0);
                    acc[lt][jt] = __builtin_amdgcn_mfma_f32_16x16x32_f16(
                        al[lt], bh_[jt], acc[lt][jt], 0, 0, 0);
                }
        }
    }

    // Epilogue: bias add, split to hi/lo, LDS transpose for coalesced stores.
    const int PSTR = 72;
    f16* tile = lds + wid * 64 * PSTR;
    const int ebase = e0 + wc * 64;
    const bool isQ = (blockIdx.y < 4);
    const int colbase = (blockIdx.y & 3) * 128;

#pragma unroll
    for (int round = 0; round < 2; round++) {
        __syncthreads();
#pragma unroll
        for (int jt = 0; jt < 4; jt++) {
            const float bval = biascat[ebase + jt * 16 + lrow];
#pragma unroll
            for (int lt = 0; lt < 4; lt++)
#pragma unroll
                for (int r = 0; r < 4; r++) {
                    const float y = acc[lt][jt][r] + bval;
                    const f16 hi = (f16)y;
                    const f16 val = (round == 0) ? hi : (f16)(y - (float)hi);
                    tile[(lt * 16 + lk * 4 + r) * PSTR + jt * 16 + lrow] = val;
                }
        }
        __syncthreads();
        f16* dst = isQ ? ((round == 0) ? qh : ql) : ((round == 0) ? kh : kl);
        for (int i = t; i < 2048; i += 256) {
            const int w = i >> 9, rem = i & 511, row = rem >> 3, c = rem & 7;
            const int n = n0 + (w >> 1) * 64 + row;
            const int col = colbase + (w & 1) * 64 + c * 8;
            *(uint4*)&dst[(size_t)n * 512 + col] =
                *(const uint4*)&lds[w * 64 * PSTR + row * PSTR + c * 8];
        }
    }
}

// ---------------------------------------------------------------------------
__global__ __launch_bounds__(256) void kbar_part_kernel(
    const f16* __restrict__ kh, const f16* __restrict__ kl,
    const int* __restrict__ counts, float* __restrict__ kbar_part)
{
    const int bh = blockIdx.x, c = blockIdx.y;
    const int b = bh >> 3, h = bh & 7;
    const int j0 = c * 256;
    const int t = threadIdx.x;
    const int e = t & 63, jg = t >> 6;
    const f16* kbh = kh + (size_t)b * L_ * D_ + h * DK + e;
    const f16* kbl = kl + (size_t)b * L_ * D_ + h * DK + e;
    float s = 0.f;
    for (int j = j0 + jg; j < j0 + 256; j += 4) {
        const float kv = (float)kbh[(size_t)j * D_] + (float)kbl[(size_t)j * D_];
        s += (float)counts[j] * kv;
    }
    __shared__ float red[4][64];
    red[jg][e] = s;
    __syncthreads();
    if (t < 64)
        kbar_part[(size_t)(bh * 8 + c) * 64 + t] =
            red[0][t] + red[1][t] + red[2][t] + red[3][t];
}

// ---------------------------------------------------------------------------
// mstat: per (l-chunk128, bh, j-half) block. q frags in registers, K
// double-buffered in LDS (1 barrier/iter), 8 j-tiles per block.
// Fused: masked row-max (split-f16 MFMA), q.kbar dot, block argmax.
// ---------------------------------------------------------------------------
__global__ __launch_bounds__(256) void mstat_kernel(
    const f16* __restrict__ qh, const f16* __restrict__ ql,
    const f16* __restrict__ kh, const f16* __restrict__ kl,
    const int* __restrict__ counts, const float* __restrict__ kbar_part,
    float* __restrict__ bestv, int* __restrict__ besti)
{
    // XCD swizzle: 512 blocks, XCD x (= id&7) gets bh {2x, 2x+1}
    const int id = blockIdx.x;
    const int xcd = id & 7, seq = id >> 3;       // seq 0..63
    const int bh = xcd * 2 + (seq >> 5);
    const int inner = seq & 31;
    const int lt16 = inner >> 1;                 // 0..15
    const int js = inner & 1;                    // 0..1
    const int jbase = js * 8;                    // j-tiles jbase..jbase+7
    const int b = bh >> 3, h = bh & 7;
    const int l0 = lt16 * 128;
    const int t = threadIdx.x;
    const int lane = t & 63, wid = t >> 6;
    const int wr = wid >> 1, wc = wid & 1;
    const int lrow = lane & 15, lk = lane >> 4;

    __shared__ __align__(16) f16 kbuf[2][2][128 * 64];  // [dbuf][hi/lo] 64 KB
    __shared__ float kbar_lds[64];
    __shared__ float dot_lds[128];
    __shared__ float wv_[4];
    __shared__ int wi_[4];

    // q fragments in registers (loaded once)
    f16x8 qa_h[2][4], qa_l[2][4];
    {
        const size_t qrowbase = (size_t)(b * L_ + l0 + wr * 64) * D_ + h * DK;
#pragma unroll
        for (int kk = 0; kk < 2; kk++)
#pragma unroll
            for (int lt = 0; lt < 4; lt++) {
                const size_t o = qrowbase + (size_t)(lt * 16 + lrow) * D_ + kk * 32 + lk * 8;
                qa_h[kk][lt] = *(const f16x8*)&qh[o];
                qa_l[kk][lt] = *(const f16x8*)&ql[o];
            }
    }
    if (t < 64) {
        float s = 0.f;
#pragma unroll
        for (int p = 0; p < 8; p++) s += kbar_part[(size_t)(bh * 8 + p) * 64 + t];
        kbar_lds[t] = s * (1.0f / (float)S_);
    }

    const f16* khb = kh + (size_t)b * L_ * D_ + h * DK;
    const f16* klb = kl + (size_t)b * L_ * D_ + h * DK;

    uint4 rh[4], rl[4];
    // prologue: stage tile jbase
#pragma unroll
    for (int i = 0; i < 4; i++) {
        const int g = i * 256 + t, row = g >> 3, c = g & 7;
        const size_t go = (size_t)(jbase * 128 + row) * D_ + c * 8;
        rh[i] = *(const uint4*)&khb[go];
        rl[i] = *(const uint4*)&klb[go];
    }
#pragma unroll
    for (int i = 0; i < 4; i++) {
        const int g = i * 256 + t, row = g >> 3, c = g & 7;
        const int cs = c ^ (row & 7);
        *(uint4*)&kbuf[0][0][row * 64 + cs * 8] = rh[i];
        *(uint4*)&kbuf[0][1][row * 64 + cs * 8] = rl[i];
    }
    __syncthreads();

    float rmax[4][4];
#pragma unroll
    for (int lt = 0; lt < 4; lt++)
#pragma unroll
        for (int r = 0; r < 4; r++) rmax[lt][r] = -3.9e38f;

    int cur = 0;
    for (int jj = 0; jj < 8; jj++) {
        const int jt = jbase + jj;
        // issue next-tile global loads (latency hides under MFMA)
        if (jj < 7) {
            const size_t kbase = (size_t)((jt + 1) * 128) * D_;
#pragma unroll
            for (int i = 0; i < 4; i++) {
                const int g = i * 256 + t, row = g >> 3, c = g & 7;
                const size_t go = kbase + (size_t)row * D_ + c * 8;
                rh[i] = *(const uint4*)&khb[go];
                rl[i] = *(const uint4*)&klb[go];
            }
        }

        f32x4 acc[4][4];
#pragma unroll
        for (int i = 0; i < 4; i++)
#pragma unroll
            for (int j = 0; j < 4; j++)
#pragma unroll
                for (int r = 0; r < 4; r++) acc[i][j][r] = 0.f;

#pragma unroll
        for (int kk = 0; kk < 2; kk++) {
            f16x8 bhf[4], blf[4];
#pragma unroll
            for (int jtt = 0; jtt < 4; jtt++) {
                const int row = wc * 64 + jtt * 16 + lrow;
                const int cs = (kk * 4 + lk) ^ (row & 7);
                const int o = row * 64 + cs * 8;
                bhf[jtt] = *(const f16x8*)&kbuf[cur][0][o];
                blf[jtt] = *(const f16x8*)&kbuf[cur][1][o];
            }
#pragma unroll
            for (int lt = 0; lt < 4; lt++)
#pragma unroll
                for (int jtt = 0; jtt < 4; jtt++) {
                    acc[lt][jtt] = __builtin_amdgcn_mfma_f32_16x16x32_f16(
                        qa_h[kk][lt], bhf[jtt], acc[lt][jtt], 0, 0, 0);
                    acc[lt][jtt] = __builtin_amdgcn_mfma_f32_16x16x32_f16(
                        qa_h[kk][lt], blf[jtt], acc[lt][jtt], 0, 0, 0);
                    acc[lt][jtt] = __builtin_amdgcn_mfma_f32_16x16x32_f16(
                        qa_l[kk][lt], bhf[jtt], acc[lt][jtt], 0, 0, 0);
                }
        }

        // masked max
#pragma unroll
        for (int jtt = 0; jtt < 4; jtt++) {
            const int cj = jt * 128 + wc * 64 + jtt * 16 + lrow;
            const float addend = (counts[cj] > 0) ? 0.f : -3.0e38f;
#pragma unroll
            for (int lt = 0; lt < 4; lt++)
#pragma unroll
                for (int r = 0; r < 4; r++)
                    rmax[lt][r] = fmaxf(rmax[lt][r], acc[lt][jtt][r] + addend);
        }

        // write next tile into the other buffer; 1 barrier per iteration
        if (jj < 7) {
#pragma unroll
            for (int i = 0; i < 4; i++) {
                const int g = i * 256 + t, row = g >> 3, c = g & 7;
                const int cs = c ^ (row & 7);
                *(uint4*)&kbuf[cur ^ 1][0][row * 64 + cs * 8] = rh[i];
                *(uint4*)&kbuf[cur ^ 1][1][row * 64 + cs * 8] = rl[i];
            }
        }
        __syncthreads();
        cur ^= 1;
    }

    // reduce row-max across the 16 column-lanes
#pragma unroll
    for (int m = 1; m < 16; m <<= 1)
#pragma unroll
        for (int lt = 0; lt < 4; lt++)
#pragma unroll
            for (int r = 0; r < 4; r++)
                rmax[lt][r] = fmaxf(rmax[lt][r], __shfl_xor(rmax[lt][r], m));

    // q.kbar dot from registers
    {
        float dlt[4];
#pragma unroll
        for (int lt = 0; lt < 4; lt++) {
            float d = 0.f;
#pragma unroll
            for (int kk = 0; kk < 2; kk++) {
                const f16x8 hv = qa_h[kk][lt];
                const f16x8 lv = qa_l[kk][lt];
#pragma unroll
                for (int i = 0; i < 8; i++)
                    d += ((float)hv[i] + (float)lv[i]) * kbar_lds[kk * 32 + lk * 8 + i];
            }
            dlt[lt] = d;
        }
#pragma unroll
        for (int lt = 0; lt < 4; lt++) {
            dlt[lt] += __shfl_xor(dlt[lt], 16);
            dlt[lt] += __shfl_xor(dlt[lt], 32);
        }
        if (lane < 16) {
#pragma unroll
            for (int lt = 0; lt < 4; lt++)
                dot_lds[wr * 64 + lt * 16 + lane] = dlt[lt];
        }
    }
    __syncthreads();

    // block argmax of (rmax - dot)
    float bv_ = -3.9e38f;
    int bi_ = 0x7fffffff;
#pragma unroll
    for (int lt = 0; lt < 4; lt++)
#pragma unroll
        for (int r = 0; r < 4; r++) {
            const int rl_ = wr * 64 + lt * 16 + lk * 4 + r;
            const float val = rmax[lt][r] - dot_lds[rl_];
            const int idx = l0 + rl_;
            if (val > bv_ || (val == bv_ && idx < bi_)) { bv_ = val; bi_ = idx; }
        }
#pragma unroll
    for (int m = 1; m < 64; m <<= 1) {
        const float ov = __shfl_xor(bv_, m);
        const int oi = __shfl_xor(bi_, m);
        if (ov > bv_ || (ov == bv_ && oi < bi_)) { bv_ = ov; bi_ = oi; }
    }
    if (lane == 0) { wv_[wid] = bv_; wi_[wid] = bi_; }
    __syncthreads();
    if (t == 0) {
        float fb = wv_[0]; int fi = wi_[0];
#pragma unroll
        for (int w = 1; w < 4; w++) {
            if (wv_[w] > fb || (wv_[w] == fb && wi_[w] < fi)) { fb = wv_[w]; fi = wi_[w]; }
        }
        bestv[bh * 32 + lt16 * 2 + js] = fb;
        besti[bh * 32 + lt16 * 2 + js] = fi;
    }
}

// ---------------------------------------------------------------------------
// final argmax over 32 chunks; strict > + min-index tie-break = first occurrence
// ---------------------------------------------------------------------------
__global__ void argmax2_kernel(const float* __restrict__ bestv,
                               const int* __restrict__ besti, int* __restrict__ U)
{
    const int t = threadIdx.x;
    if (t < 16) {
        float best = -3.9e38f;
        int bi = 0x7fffffff;
#pragma unroll
        for (int c = 0; c < 32; c++) {
            const float v = bestv[t * 32 + c];
            const int oi = besti[t * 32 + c];
            if (v > best || (v == best && oi < bi)) { best = v; bi = oi; }
        }
        U[t] = bi;
    }
}

// ---------------------------------------------------------------------------
// ctx stage 1: scores from kh/kl . q_u, softmax partials, x-weighted partial
// (context = (sum_l attn_l x_l) . Wv + bv  since sum attn = 1)
// ---------------------------------------------------------------------------
__global__ __launch_bounds__(256) void ctx_part_kernel(
    const f16* __restrict__ qh, const f16* __restrict__ ql,
    const f16* __restrict__ kh, const f16* __restrict__ kl,
    const float* __restrict__ x, const int* __restrict__ U,
    float* __restrict__ xbar_part, float* __restrict__ cm, float* __restrict__ cs)
{
    const int bh = blockIdx.x, c = blockIdx.y;   // 16 x 16
    const int b = bh >> 3, h = bh & 7;
    const int l0 = c * 128;
    const int t = threadIdx.x;

    __shared__ float qr[64];
    __shared__ float w[128];
    __shared__ float red[128];

    const int u = U[bh];
    if (t < 64)
        qr[t] = (float)qh[(size_t)(b * L_ + u) * D_ + h * DK + t] +
                (float)ql[(size_t)(b * L_ + u) * D_ + h * DK + t];
    __syncthreads();

    {
        const int row = t >> 1, half = t & 1;
        const size_t off = (size_t)(b * L_ + l0 + row) * D_ + h * DK + half * 32;
        const f16* krh = kh + off;
        const f16* krl = kl + off;
        float dot = 0.f;
#pragma unroll
        for (int cc = 0; cc < 4; cc++) {
            const f16x8 hv = *(const f16x8*)&krh[cc * 8];
            const f16x8 lv = *(const f16x8*)&krl[cc * 8];
#pragma unroll
            for (int i = 0; i < 8; i++)
                dot += ((float)hv[i] + (float)lv[i]) * qr[half * 32 + cc * 8 + i];
        }
        dot += __shfl_xor(dot, 1);
        if (half == 0) w[row] = dot * SCALE;
    }
    __syncthreads();

    if (t < 128) red[t] = w[t];
    __syncthreads();
    for (int s = 64; s > 0; s >>= 1) {
        if (t < s) red[t] = fmaxf(red[t], red[t + s]);
        __syncthreads();
    }
    const float m = red[0];
    __syncthreads();

    if (t < 128) { const float e = expf(w[t] - m); w[t] = e; red[t] = e; }
    __syncthreads();
    for (int s = 64; s > 0; s >>= 1) {
        if (t < s) red[t] += red[t + s];
        __syncthreads();
    }
    const float ssum = red[0];

    float ax = 0.f, ay = 0.f;
    const float* xb = x + (size_t)(b * L_ + l0) * D_ + t * 2;
#pragma unroll 4
    for (int l = 0; l < 128; l++) {
        const float wl = w[l];
        const float2 xv = *(const float2*)(xb + (size_t)l * D_);
        ax = fmaf(wl, xv.x, ax);
        ay = fmaf(wl, xv.y, ay);
    }
    float2 st; st.x = ax; st.y = ay;
    *(float2*)&xbar_part[(size_t)(bh * 16 + c) * 512 + t * 2] = st;
    if (t == 0) { cm[bh * 16 + c] = m; cs[bh * 16 + c] = ssum; }
}

// ---------------------------------------------------------------------------
__global__ __launch_bounds__(256) void ctx_combine_kernel(
    const float* __restrict__ xbar_part, const float* __restrict__ cm,
    const float* __restrict__ cs, const float* __restrict__ Wv,
    const float* __restrict__ bv, float* __restrict__ ctx)
{
    const int bh = blockIdx.x;
    const int h = bh & 7;
    const int t = threadIdx.x;
    __shared__ float xbar[512];

    float M = -3.9e38f;
#pragma unroll
    for (int c = 0; c < 16; c++) M = fmaxf(M, cm[bh * 16 + c]);
    float denom = 0.f;
    float ax = 0.f, ay = 0.f;
#pragma unroll
    for (int c = 0; c < 16; c++) {
        const float f = expf(cm[bh * 16 + c] - M);
        denom += f * cs[bh * 16 + c];
        const float2 p = *(const float2*)&xbar_part[(size_t)(bh * 16 + c) * 512 + t * 2];
        ax = fmaf(f, p.x, ax);
        ay = fmaf(f, p.y, ay);
    }
    xbar[t * 2] = ax; xbar[t * 2 + 1] = ay;
    __syncthreads();

    if (t < 64) {
        const float* wr = Wv + (size_t)(h * 64 + t) * D_;
        float acc = 0.f;
#pragma unroll 8
        for (int d = 0; d < 128; d++) {
            const float4 wv4 = *(const float4*)&wr[d * 4];
            acc += wv4.x * xbar[d * 4] + wv4.y * xbar[d * 4 + 1] +
                   wv4.z * xbar[d * 4 + 2] + wv4.w * xbar[d * 4 + 3];
        }
        ctx[bh * 64 + t] = acc / denom + bv[h * 64 + t];
    }
}

// ---------------------------------------------------------------------------
__global__ __launch_bounds__(256) void out_row_kernel(
    const float* __restrict__ ctx, const float* __restrict__ Wo,
    const float* __restrict__ bo, float* __restrict__ rowbuf)
{
    const int b = blockIdx.x;
    const int t = threadIdx.x;
    __shared__ float cb[512];
    cb[t] = ctx[b * 512 + t];
    cb[t + 256] = ctx[b * 512 + 256 + t];
    __syncthreads();
#pragma unroll
    for (int r = 0; r < 2; r++) {
        const int e = t + r * 256;
        const float* wr = Wo + (size_t)e * D_;
        float acc = 0.f;
#pragma unroll 8
        for (int c = 0; c < 128; c++) {
            const float4 wv = *(const float4*)(wr + c * 4);
            acc += wv.x * cb[c * 4] + wv.y * cb[c * 4 + 1] +
                   wv.z * cb[c * 4 + 2] + wv.w * cb[c * 4 + 3];
        }
        rowbuf[b * 512 + e] = acc + bo[e];
    }
}

// ---------------------------------------------------------------------------
__global__ __launch_bounds__(256) void out_bcast_kernel(
    const float* __restrict__ rowbuf, float* __restrict__ out)
{
    const int g = blockIdx.x * 256 + threadIdx.x;   // float4 index, 524288 total
    const int l = g >> 7, c = g & 127;
    const int b = l >> 11;
    ((float4*)out)[g] = ((const float4*)rowbuf)[b * 128 + c];
}

// ---------------------------------------------------------------------------
extern "C" void kernel_launch(void* const* d_in, const int* in_sizes, int n_in,
                              void* d_out, int out_size, void* d_ws, size_t ws_size,
                              hipStream_t stream)
{
    const float* x   = (const float*)d_in[0];
    const int* samp  = (const int*)d_in[1];
    const float* Wq  = (const float*)d_in[2];
    const float* bq  = (const float*)d_in[3];
    const float* Wk  = (const float*)d_in[4];
    const float* bk  = (const float*)d_in[5];
    const float* Wv  = (const float*)d_in[6];
    const float* bv  = (const float*)d_in[7];
    const float* Wo  = (const float*)d_in[8];
    const float* bo  = (const float*)d_in[9];
    float* out = (float*)d_out;

    f16* qh = (f16*)d_ws;
    f16* ql = qh + QSZ;
    f16* kh = ql + QSZ;
    f16* kl = kh + QSZ;
    f16* xh = kl + QSZ;
    f16* xl = xh + QSZ;
    f16* wh = xl + QSZ;                       // 1024*512
    f16* wl = wh + 1024 * 512;
    float* fbase     = (float*)(wl + 1024 * 512);
    float* biascat   = fbase;                 // 1024
    float* kbar_part = biascat + 1024;        // 8192
    float* xbar_part = kbar_part + 8192;      // 131072
    float* cm        = xbar_part + 131072;    // 256
    float* cs        = cm + 256;              // 256
    float* bestv     = cs + 256;              // 512
    float* ctx       = bestv + 512;           // 1024
    float* rowbuf    = ctx + 1024;            // 1024
    int* counts      = (int*)(rowbuf + 1024); // 2048
    int* besti       = counts + 2048;         // 512
    int* U           = besti + 512;           // 16

    hipMemsetAsync(counts, 0, 2048 * sizeof(int), stream);
    prep_kernel<<<1320, 256, 0, stream>>>(x, Wq, Wk, bq, bk, samp,
                                          xh, xl, wh, wl, biascat, counts);
    projqk_kernel<<<dim3(32, 8), 256, 0, stream>>>(xh, xl, wh, wl, biascat,
                                                   qh, ql, kh, kl);
    kbar_part_kernel<<<dim3(16, 8), 256, 0, stream>>>(kh, kl, counts, kbar_part);
    mstat_kernel<<<512, 256, 0, stream>>>(qh, ql, kh, kl, counts, kbar_part,
                                          bestv, besti);
    argmax2_kernel<<<1, 64, 0, stream>>>(bestv, besti, U);
    ctx_part_kernel<<<dim3(16, 16), 256, 0, stream>>>(qh, ql, kh, kl, x, U,
                                                      xbar_part, cm, cs);
    ctx_combine_kernel<<<16, 256, 0, stream>>>(xbar_part, cm, cs, Wv, bv, ctx);
    out_row_kernel<<<2, 256, 0, stream>>>(ctx, Wo, bo, rowbuf);
    out_bcast_kernel<<<2048, 256, 0, stream>>>(rowbuf, out);
}

// Round 7
// 151.248 us; speedup vs baseline: 1.3621x; 1.1981x over previous
//
#include <hip/hip_runtime.h>

#define B_ 2
#define L_ 2048
#define D_ 512
#define H_ 8
#define DK 64
#define S_ 10240
#define SCALE 0.125f

#define QSZ (4096 * 512)  // B_*L_*D_ elements

typedef _Float16 f16;
typedef __attribute__((ext_vector_type(8))) _Float16 f16x8;
typedef __attribute__((ext_vector_type(4))) float f32x4;

#define AS1 __attribute__((address_space(1)))
#define AS3 __attribute__((address_space(3)))

// ---------------------------------------------------------------------------
// prep: split x -> xh/xl, split Wq|Wk -> wh/wl + biascat, histogram of samp
// ---------------------------------------------------------------------------
__global__ __launch_bounds__(256) void prep_kernel(
    const float* __restrict__ x,
    const float* __restrict__ Wq, const float* __restrict__ Wk,
    const float* __restrict__ bq, const float* __restrict__ bk,
    const int* __restrict__ samp,
    f16* __restrict__ xh, f16* __restrict__ xl,
    f16* __restrict__ wh, f16* __restrict__ wl,
    float* __restrict__ biascat, int* __restrict__ counts)
{
    const int bid = blockIdx.x;
    const int t = threadIdx.x;
    if (bid < 1024) {
        const size_t i0 = ((size_t)bid * 256 + t) * 8;
        const float4 a = *(const float4*)&x[i0];
        const float4 b = *(const float4*)&x[i0 + 4];
        const float vals[8] = {a.x, a.y, a.z, a.w, b.x, b.y, b.z, b.w};
        union { f16 h[8]; uint4 u; } H, Lo;
#pragma unroll
        for (int j = 0; j < 8; j++) {
            const f16 hh = (f16)vals[j];
            H.h[j] = hh;
            Lo.h[j] = (f16)(vals[j] - (float)hh);
        }
        *(uint4*)&xh[i0] = H.u;
        *(uint4*)&xl[i0] = Lo.u;
    } else if (bid < 1280) {
        const size_t i0 = ((size_t)(bid - 1024) * 256 + t) * 8;
        const float* src = (i0 < (size_t)512 * 512) ? Wq + i0
                                                    : Wk + (i0 - (size_t)512 * 512);
        const float4 a = *(const float4*)&src[0];
        const float4 b = *(const float4*)&src[4];
        const float vals[8] = {a.x, a.y, a.z, a.w, b.x, b.y, b.z, b.w};
        union { f16 h[8]; uint4 u; } H, Lo;
#pragma unroll
        for (int j = 0; j < 8; j++) {
            const f16 hh = (f16)vals[j];
            H.h[j] = hh;
            Lo.h[j] = (f16)(vals[j] - (float)hh);
        }
        *(uint4*)&wh[i0] = H.u;
        *(uint4*)&wl[i0] = Lo.u;
        if (bid == 1024)
            for (int e = t; e < 1024; e += 256)
                biascat[e] = (e < 512) ? bq[e] : bk[e - 512];
    } else {
        const int i = (bid - 1280) * 256 + t;
        if (i < S_) atomicAdd(&counts[samp[i]], 1);
    }
}

// ---------------------------------------------------------------------------
// q,k projections via split-f16 MFMA GEMM: [4096 x 512] . [512 x 1024]^T
// ---------------------------------------------------------------------------
__global__ __launch_bounds__(256) void projqk_kernel(
    const f16* __restrict__ xh, const f16* __restrict__ xl,
    const f16* __restrict__ wh, const f16* __restrict__ wl,
    const float* __restrict__ biascat,
    f16* __restrict__ qh, f16* __restrict__ ql,
    f16* __restrict__ kh, f16* __restrict__ kl)
{
    const int n0 = blockIdx.x * 128;   // rows (tokens)
    const int e0 = blockIdx.y * 128;   // cols (proj dims, 0..1023)
    const int t = threadIdx.x;

    __shared__ __align__(16) f16 lds[4 * 128 * 64];   // 64 KB
    f16* ash = lds;
    f16* asl = lds + 8192;
    f16* bsh = lds + 16384;
    f16* bsl = lds + 24576;

    const int lane = t & 63, wid = t >> 6;
    const int wr = wid >> 1, wc = wid & 1;
    const int lrow = lane & 15, lk = lane >> 4;

    f32x4 acc[4][4];
#pragma unroll
    for (int i = 0; i < 4; i++)
#pragma unroll
        for (int j = 0; j < 4; j++)
#pragma unroll
            for (int r = 0; r < 4; r++) acc[i][j][r] = 0.f;

    for (int kt = 0; kt < 8; kt++) {
        __syncthreads();
#pragma unroll
        for (int i = 0; i < 4; i++) {
            const int g = i * 256 + t;
            const int row = g >> 3, c = g & 7;
            const int cs = c ^ (row & 7);
            const int lo = row * 64 + cs * 8;
            const size_t ga = (size_t)(n0 + row) * 512 + kt * 64 + c * 8;
            const size_t gb = (size_t)(e0 + row) * 512 + kt * 64 + c * 8;
            *(uint4*)&ash[lo] = *(const uint4*)&xh[ga];
            *(uint4*)&asl[lo] = *(const uint4*)&xl[ga];
            *(uint4*)&bsh[lo] = *(const uint4*)&wh[gb];
            *(uint4*)&bsl[lo] = *(const uint4*)&wl[gb];
        }
        __syncthreads();

#pragma unroll
        for (int kk = 0; kk < 2; kk++) {
            f16x8 ah[4], al[4], bh_[4], bl_[4];
#pragma unroll
            for (int lt = 0; lt < 4; lt++) {
                const int row = wr * 64 + lt * 16 + lrow;
                const int cs = (kk * 4 + lk) ^ (row & 7);
                const int o = row * 64 + cs * 8;
                ah[lt] = *(const f16x8*)&ash[o];
                al[lt] = *(const f16x8*)&asl[o];
            }
#pragma unroll
            for (int jt = 0; jt < 4; jt++) {
                const int row = wc * 64 + jt * 16 + lrow;
                const int cs = (kk * 4 + lk) ^ (row & 7);
                const int o = row * 64 + cs * 8;
                bh_[jt] = *(const f16x8*)&bsh[o];
                bl_[jt] = *(const f16x8*)&bsl[o];
            }
#pragma unroll
            for (int lt = 0; lt < 4; lt++)
#pragma unroll
                for (int jt = 0; jt < 4; jt++) {
                    acc[lt][jt] = __builtin_amdgcn_mfma_f32_16x16x32_f16(
                        ah[lt], bh_[jt], acc[lt][jt], 0, 0, 0);
                    acc[lt][jt] = __builtin_amdgcn_mfma_f32_16x16x32_f16(
                        ah[lt], bl_[jt], acc[lt][jt], 0, 0, 0);
                    acc[lt][jt] = __builtin_amdgcn_mfma_f32_16x16x32_f16(
                        al[lt], bh_[jt], acc[lt][jt], 0, 0, 0);
                }
        }
    }

    // Epilogue: bias add, split to hi/lo, LDS transpose for coalesced stores.
    const int PSTR = 72;
    f16* tile = lds + wid * 64 * PSTR;
    const int ebase = e0 + wc * 64;
    const bool isQ = (blockIdx.y < 4);
    const int colbase = (blockIdx.y & 3) * 128;

#pragma unroll
    for (int round = 0; round < 2; round++) {
        __syncthreads();
#pragma unroll
        for (int jt = 0; jt < 4; jt++) {
            const float bval = biascat[ebase + jt * 16 + lrow];
#pragma unroll
            for (int lt = 0; lt < 4; lt++)
#pragma unroll
                for (int r = 0; r < 4; r++) {
                    const float y = acc[lt][jt][r] + bval;
                    const f16 hi = (f16)y;
                    const f16 val = (round == 0) ? hi : (f16)(y - (float)hi);
                    tile[(lt * 16 + lk * 4 + r) * PSTR + jt * 16 + lrow] = val;
                }
        }
        __syncthreads();
        f16* dst = isQ ? ((round == 0) ? qh : ql) : ((round == 0) ? kh : kl);
        for (int i = t; i < 2048; i += 256) {
            const int w = i >> 9, rem = i & 511, row = rem >> 3, c = rem & 7;
            const int n = n0 + (w >> 1) * 64 + row;
            const int col = colbase + (w & 1) * 64 + c * 8;
            *(uint4*)&dst[(size_t)n * 512 + col] =
                *(const uint4*)&lds[w * 64 * PSTR + row * PSTR + c * 8];
        }
    }
}

// ---------------------------------------------------------------------------
__global__ __launch_bounds__(256) void kbar_part_kernel(
    const f16* __restrict__ kh, const f16* __restrict__ kl,
    const int* __restrict__ counts, float* __restrict__ kbar_part)
{
    const int bh = blockIdx.x, c = blockIdx.y;
    const int b = bh >> 3, h = bh & 7;
    const int j0 = c * 256;
    const int t = threadIdx.x;
    const int e = t & 63, jg = t >> 6;
    const f16* kbh = kh + (size_t)b * L_ * D_ + h * DK + e;
    const f16* kbl = kl + (size_t)b * L_ * D_ + h * DK + e;
    float s = 0.f;
    for (int j = j0 + jg; j < j0 + 256; j += 4) {
        const float kv = (float)kbh[(size_t)j * D_] + (float)kbl[(size_t)j * D_];
        s += (float)counts[j] * kv;
    }
    __shared__ float red[4][64];
    red[jg][e] = s;
    __syncthreads();
    if (t < 64)
        kbar_part[(size_t)(bh * 8 + c) * 64 + t] =
            red[0][t] + red[1][t] + red[2][t] + red[3][t];
}

// ---------------------------------------------------------------------------
// mstat: per (l-chunk128, bh, j-half) block. q frags in registers, K staged
// HBM->LDS via global_load_lds (no staging VGPRs), double-buffered,
// pre-swizzled global source preserves the XOR LDS swizzle.
// ---------------------------------------------------------------------------
__global__ __launch_bounds__(256, 2) void mstat_kernel(
    const f16* __restrict__ qh, const f16* __restrict__ ql,
    const f16* __restrict__ kh, const f16* __restrict__ kl,
    const int* __restrict__ counts, const float* __restrict__ kbar_part,
    float* __restrict__ bestv, int* __restrict__ besti)
{
    // XCD swizzle: 512 blocks, XCD x (= id&7) gets bh {2x, 2x+1}
    const int id = blockIdx.x;
    const int xcd = id & 7, seq = id >> 3;       // seq 0..63
    const int bh = xcd * 2 + (seq >> 5);
    const int inner = seq & 31;
    const int lt16 = inner >> 1;                 // 0..15
    const int js = inner & 1;                    // 0..1
    const int jbase = js * 8;                    // j-tiles jbase..jbase+7
    const int b = bh >> 3, h = bh & 7;
    const int l0 = lt16 * 128;
    const int t = threadIdx.x;
    const int lane = t & 63, wid = t >> 6;
    const int wr = wid >> 1, wc = wid & 1;
    const int lrow = lane & 15, lk = lane >> 4;

    __shared__ __align__(16) f16 kbuf[2][2][128 * 64];  // [dbuf][hi/lo] 64 KB
    __shared__ float kbar_lds[64];
    __shared__ float dot_lds[128];
    __shared__ float wv_[4];
    __shared__ int wi_[4];

    // q fragments in registers (loaded once)
    f16x8 qa_h[2][4], qa_l[2][4];
    {
        const size_t qrowbase = (size_t)(b * L_ + l0 + wr * 64) * D_ + h * DK;
#pragma unroll
        for (int kk = 0; kk < 2; kk++)
#pragma unroll
            for (int lt = 0; lt < 4; lt++) {
                const size_t o = qrowbase + (size_t)(lt * 16 + lrow) * D_ + kk * 32 + lk * 8;
                qa_h[kk][lt] = *(const f16x8*)&qh[o];
                qa_l[kk][lt] = *(const f16x8*)&ql[o];
            }
    }
    if (t < 64) {
        float s = 0.f;
#pragma unroll
        for (int p = 0; p < 8; p++) s += kbar_part[(size_t)(bh * 8 + p) * 64 + t];
        kbar_lds[t] = s * (1.0f / (float)S_);
    }

    const f16* khb = kh + (size_t)b * L_ * D_ + h * DK;
    const f16* klb = kl + (size_t)b * L_ * D_ + h * DK;

    // async stage of one 128x64 hi/lo tile pair into kbuf[nb].
    // Linear LDS dest (wave-uniform base + lane*16B) + pre-swizzled global
    // column: lane l reads col chunk (l&7)^(l>>3) of row chunk*8+(l>>3),
    // which lands as LDS[row][cs] = G[row][cs ^ (row&7)]  (the read swizzle).
    const int srw = lane >> 3;               // row-in-chunk
    const int scg = (lane & 7) ^ srw;        // swizzled global col chunk
#define STAGE_TILE(jt, nb)                                                     \
    {                                                                          \
        const size_t gb0 = (size_t)((jt) * 128) * D_;                          \
        _Pragma("unroll")                                                      \
        for (int i_ = 0; i_ < 4; i_++) {                                       \
            const int chunk = wid * 4 + i_;                                    \
            const size_t go = gb0 + (size_t)(chunk * 8 + srw) * D_ + scg * 8;  \
            __builtin_amdgcn_global_load_lds(                                  \
                (const AS1 void*)(khb + go),                                   \
                (AS3 void*)(&kbuf[nb][0][chunk * 512]), 16, 0, 0);             \
            __builtin_amdgcn_global_load_lds(                                  \
                (const AS1 void*)(klb + go),                                   \
                (AS3 void*)(&kbuf[nb][1][chunk * 512]), 16, 0, 0);             \
        }                                                                      \
    }

    STAGE_TILE(jbase, 0)
    __syncthreads();

    float rmax[4][4];
#pragma unroll
    for (int lt = 0; lt < 4; lt++)
#pragma unroll
        for (int r = 0; r < 4; r++) rmax[lt][r] = -3.9e38f;

    int cur = 0;
    for (int jj = 0; jj < 8; jj++) {
        const int jt = jbase + jj;
        if (jj < 7) STAGE_TILE(jt + 1, cur ^ 1)

        f32x4 acc[4][4];
#pragma unroll
        for (int i = 0; i < 4; i++)
#pragma unroll
            for (int j = 0; j < 4; j++)
#pragma unroll
                for (int r = 0; r < 4; r++) acc[i][j][r] = 0.f;

#pragma unroll
        for (int kk = 0; kk < 2; kk++) {
            f16x8 bhf[4], blf[4];
#pragma unroll
            for (int jtt = 0; jtt < 4; jtt++) {
                const int row = wc * 64 + jtt * 16 + lrow;
                const int cs = (kk * 4 + lk) ^ (row & 7);
                const int o = row * 64 + cs * 8;
                bhf[jtt] = *(const f16x8*)&kbuf[cur][0][o];
                blf[jtt] = *(const f16x8*)&kbuf[cur][1][o];
            }
#pragma unroll
            for (int lt = 0; lt < 4; lt++)
#pragma unroll
                for (int jtt = 0; jtt < 4; jtt++) {
                    acc[lt][jtt] = __builtin_amdgcn_mfma_f32_16x16x32_f16(
                        qa_h[kk][lt], bhf[jtt], acc[lt][jtt], 0, 0, 0);
                    acc[lt][jtt] = __builtin_amdgcn_mfma_f32_16x16x32_f16(
                        qa_h[kk][lt], blf[jtt], acc[lt][jtt], 0, 0, 0);
                    acc[lt][jtt] = __builtin_amdgcn_mfma_f32_16x16x32_f16(
                        qa_l[kk][lt], bhf[jtt], acc[lt][jtt], 0, 0, 0);
                }
        }

        // masked max
#pragma unroll
        for (int jtt = 0; jtt < 4; jtt++) {
            const int cj = jt * 128 + wc * 64 + jtt * 16 + lrow;
            const float addend = (counts[cj] > 0) ? 0.f : -3.0e38f;
#pragma unroll
            for (int lt = 0; lt < 4; lt++)
#pragma unroll
                for (int r = 0; r < 4; r++)
                    rmax[lt][r] = fmaxf(rmax[lt][r], acc[lt][jtt][r] + addend);
        }

        __syncthreads();   // drains vmcnt -> staged tile ready
        cur ^= 1;
    }

    // reduce row-max across the 16 column-lanes
#pragma unroll
    for (int m = 1; m < 16; m <<= 1)
#pragma unroll
        for (int lt = 0; lt < 4; lt++)
#pragma unroll
            for (int r = 0; r < 4; r++)
                rmax[lt][r] = fmaxf(rmax[lt][r], __shfl_xor(rmax[lt][r], m));

    // q.kbar dot from registers
    {
        float dlt[4];
#pragma unroll
        for (int lt = 0; lt < 4; lt++) {
            float d = 0.f;
#pragma unroll
            for (int kk = 0; kk < 2; kk++) {
                const f16x8 hv = qa_h[kk][lt];
                const f16x8 lv = qa_l[kk][lt];
#pragma unroll
                for (int i = 0; i < 8; i++)
                    d += ((float)hv[i] + (float)lv[i]) * kbar_lds[kk * 32 + lk * 8 + i];
            }
            dlt[lt] = d;
        }
#pragma unroll
        for (int lt = 0; lt < 4; lt++) {
            dlt[lt] += __shfl_xor(dlt[lt], 16);
            dlt[lt] += __shfl_xor(dlt[lt], 32);
        }
        if (lane < 16) {
#pragma unroll
            for (int lt = 0; lt < 4; lt++)
                dot_lds[wr * 64 + lt * 16 + lane] = dlt[lt];
        }
    }
    __syncthreads();

    // block argmax of (rmax - dot)
    float bv_ = -3.9e38f;
    int bi_ = 0x7fffffff;
#pragma unroll
    for (int lt = 0; lt < 4; lt++)
#pragma unroll
        for (int r = 0; r < 4; r++) {
            const int rl_ = wr * 64 + lt * 16 + lk * 4 + r;
            const float val = rmax[lt][r] - dot_lds[rl_];
            const int idx = l0 + rl_;
            if (val > bv_ || (val == bv_ && idx < bi_)) { bv_ = val; bi_ = idx; }
        }
#pragma unroll
    for (int m = 1; m < 64; m <<= 1) {
        const float ov = __shfl_xor(bv_, m);
        const int oi = __shfl_xor(bi_, m);
        if (ov > bv_ || (ov == bv_ && oi < bi_)) { bv_ = ov; bi_ = oi; }
    }
    if (lane == 0) { wv_[wid] = bv_; wi_[wid] = bi_; }
    __syncthreads();
    if (t == 0) {
        float fb = wv_[0]; int fi = wi_[0];
#pragma unroll
        for (int w = 1; w < 4; w++) {
            if (wv_[w] > fb || (wv_[w] == fb && wi_[w] < fi)) { fb = wv_[w]; fi = wi_[w]; }
        }
        bestv[bh * 32 + lt16 * 2 + js] = fb;
        besti[bh * 32 + lt16 * 2 + js] = fi;
    }
#undef STAGE_TILE
}

// ---------------------------------------------------------------------------
// final argmax over 32 chunks; strict > + min-index tie-break = first occurrence
// ---------------------------------------------------------------------------
__global__ void argmax2_kernel(const float* __restrict__ bestv,
                               const int* __restrict__ besti, int* __restrict__ U)
{
    const int t = threadIdx.x;
    if (t < 16) {
        float best = -3.9e38f;
        int bi = 0x7fffffff;
#pragma unroll
        for (int c = 0; c < 32; c++) {
            const float v = bestv[t * 32 + c];
            const int oi = besti[t * 32 + c];
            if (v > best || (v == best && oi < bi)) { best = v; bi = oi; }
        }
        U[t] = bi;
    }
}

// ---------------------------------------------------------------------------
// ctx stage 1: scores from kh/kl . q_u, softmax partials, x-weighted partial
// (context = (sum_l attn_l x_l) . Wv + bv  since sum attn = 1)
// ---------------------------------------------------------------------------
__global__ __launch_bounds__(256) void ctx_part_kernel(
    const f16* __restrict__ qh, const f16* __restrict__ ql,
    const f16* __restrict__ kh, const f16* __restrict__ kl,
    const float* __restrict__ x, const int* __restrict__ U,
    float* __restrict__ xbar_part, float* __restrict__ cm, float* __restrict__ cs)
{
    const int bh = blockIdx.x, c = blockIdx.y;   // 16 x 16
    const int b = bh >> 3, h = bh & 7;
    const int l0 = c * 128;
    const int t = threadIdx.x;

    __shared__ float qr[64];
    __shared__ float w[128];
    __shared__ float red[128];

    const int u = U[bh];
    if (t < 64)
        qr[t] = (float)qh[(size_t)(b * L_ + u) * D_ + h * DK + t] +
                (float)ql[(size_t)(b * L_ + u) * D_ + h * DK + t];
    __syncthreads();

    {
        const int row = t >> 1, half = t & 1;
        const size_t off = (size_t)(b * L_ + l0 + row) * D_ + h * DK + half * 32;
        const f16* krh = kh + off;
        const f16* krl = kl + off;
        float dot = 0.f;
#pragma unroll
        for (int cc = 0; cc < 4; cc++) {
            const f16x8 hv = *(const f16x8*)&krh[cc * 8];
            const f16x8 lv = *(const f16x8*)&krl[cc * 8];
#pragma unroll
            for (int i = 0; i < 8; i++)
                dot += ((float)hv[i] + (float)lv[i]) * qr[half * 32 + cc * 8 + i];
        }
        dot += __shfl_xor(dot, 1);
        if (half == 0) w[row] = dot * SCALE;
    }
    __syncthreads();

    if (t < 128) red[t] = w[t];
    __syncthreads();
    for (int s = 64; s > 0; s >>= 1) {
        if (t < s) red[t] = fmaxf(red[t], red[t + s]);
        __syncthreads();
    }
    const float m = red[0];
    __syncthreads();

    if (t < 128) { const float e = expf(w[t] - m); w[t] = e; red[t] = e; }
    __syncthreads();
    for (int s = 64; s > 0; s >>= 1) {
        if (t < s) red[t] += red[t + s];
        __syncthreads();
    }
    const float ssum = red[0];

    float ax = 0.f, ay = 0.f;
    const float* xb = x + (size_t)(b * L_ + l0) * D_ + t * 2;
#pragma unroll 4
    for (int l = 0; l < 128; l++) {
        const float wl = w[l];
        const float2 xv = *(const float2*)(xb + (size_t)l * D_);
        ax = fmaf(wl, xv.x, ax);
        ay = fmaf(wl, xv.y, ay);
    }
    float2 st; st.x = ax; st.y = ay;
    *(float2*)&xbar_part[(size_t)(bh * 16 + c) * 512 + t * 2] = st;
    if (t == 0) { cm[bh * 16 + c] = m; cs[bh * 16 + c] = ssum; }
}

// ---------------------------------------------------------------------------
__global__ __launch_bounds__(256) void ctx_combine_kernel(
    const float* __restrict__ xbar_part, const float* __restrict__ cm,
    const float* __restrict__ cs, const float* __restrict__ Wv,
    const float* __restrict__ bv, float* __restrict__ ctx)
{
    const int bh = blockIdx.x;
    const int h = bh & 7;
    const int t = threadIdx.x;
    __shared__ float xbar[512];

    float M = -3.9e38f;
#pragma unroll
    for (int c = 0; c < 16; c++) M = fmaxf(M, cm[bh * 16 + c]);
    float denom = 0.f;
    float ax = 0.f, ay = 0.f;
#pragma unroll
    for (int c = 0; c < 16; c++) {
        const float f = expf(cm[bh * 16 + c] - M);
        denom += f * cs[bh * 16 + c];
        const float2 p = *(const float2*)&xbar_part[(size_t)(bh * 16 + c) * 512 + t * 2];
        ax = fmaf(f, p.x, ax);
        ay = fmaf(f, p.y, ay);
    }
    xbar[t * 2] = ax; xbar[t * 2 + 1] = ay;
    __syncthreads();

    if (t < 64) {
        const float* wr = Wv + (size_t)(h * 64 + t) * D_;
        float acc = 0.f;
#pragma unroll 8
        for (int d = 0; d < 128; d++) {
            const float4 wv4 = *(const float4*)&wr[d * 4];
            acc += wv4.x * xbar[d * 4] + wv4.y * xbar[d * 4 + 1] +
                   wv4.z * xbar[d * 4 + 2] + wv4.w * xbar[d * 4 + 3];
        }
        ctx[bh * 64 + t] = acc / denom + bv[h * 64 + t];
    }
}

// ---------------------------------------------------------------------------
__global__ __launch_bounds__(256) void out_row_kernel(
    const float* __restrict__ ctx, const float* __restrict__ Wo,
    const float* __restrict__ bo, float* __restrict__ rowbuf)
{
    const int b = blockIdx.x;
    const int t = threadIdx.x;
    __shared__ float cb[512];
    cb[t] = ctx[b * 512 + t];
    cb[t + 256] = ctx[b * 512 + 256 + t];
    __syncthreads();
#pragma unroll
    for (int r = 0; r < 2; r++) {
        const int e = t + r * 256;
        const float* wr = Wo + (size_t)e * D_;
        float acc = 0.f;
#pragma unroll 8
        for (int c = 0; c < 128; c++) {
            const float4 wv = *(const float4*)(wr + c * 4);
            acc += wv.x * cb[c * 4] + wv.y * cb[c * 4 + 1] +
                   wv.z * cb[c * 4 + 2] + wv.w * cb[c * 4 + 3];
        }
        rowbuf[b * 512 + e] = acc + bo[e];
    }
}

// ---------------------------------------------------------------------------
__global__ __launch_bounds__(256) void out_bcast_kernel(
    const float* __restrict__ rowbuf, float* __restrict__ out)
{
    const int g = blockIdx.x * 256 + threadIdx.x;   // float4 index, 524288 total
    const int l = g >> 7, c = g & 127;
    const int b = l >> 11;
    ((float4*)out)[g] = ((const float4*)rowbuf)[b * 128 + c];
}

// ---------------------------------------------------------------------------
extern "C" void kernel_launch(void* const* d_in, const int* in_sizes, int n_in,
                              void* d_out, int out_size, void* d_ws, size_t ws_size,
                              hipStream_t stream)
{
    const float* x   = (const float*)d_in[0];
    const int* samp  = (const int*)d_in[1];
    const float* Wq  = (const float*)d_in[2];
    const float* bq  = (const float*)d_in[3];
    const float* Wk  = (const float*)d_in[4];
    const float* bk  = (const float*)d_in[5];
    const float* Wv  = (const float*)d_in[6];
    const float* bv  = (const float*)d_in[7];
    const float* Wo  = (const float*)d_in[8];
    const float* bo  = (const float*)d_in[9];
    float* out = (float*)d_out;

    f16* qh = (f16*)d_ws;
    f16* ql = qh + QSZ;
    f16* kh = ql + QSZ;
    f16* kl = kh + QSZ;
    f16* xh = kl + QSZ;
    f16* xl = xh + QSZ;
    f16* wh = xl + QSZ;                       // 1024*512
    f16* wl = wh + 1024 * 512;
    float* fbase     = (float*)(wl + 1024 * 512);
    float* biascat   = fbase;                 // 1024
    float* kbar_part = biascat + 1024;        // 8192
    float* xbar_part = kbar_part + 8192;      // 131072
    float* cm        = xbar_part + 131072;    // 256
    float* cs        = cm + 256;              // 256
    float* bestv     = cs + 256;              // 512
    float* ctx       = bestv + 512;           // 1024
    float* rowbuf    = ctx + 1024;            // 1024
    int* counts      = (int*)(rowbuf + 1024); // 2048
    int* besti       = counts + 2048;         // 512
    int* U           = besti + 512;           // 16

    hipMemsetAsync(counts, 0, 2048 * sizeof(int), stream);
    prep_kernel<<<1320, 256, 0, stream>>>(x, Wq, Wk, bq, bk, samp,
                                          xh, xl, wh, wl, biascat, counts);
    projqk_kernel<<<dim3(32, 8), 256, 0, stream>>>(xh, xl, wh, wl, biascat,
                                                   qh, ql, kh, kl);
    kbar_part_kernel<<<dim3(16, 8), 256, 0, stream>>>(kh, kl, counts, kbar_part);
    mstat_kernel<<<512, 256, 0, stream>>>(qh, ql, kh, kl, counts, kbar_part,
                                          bestv, besti);
    argmax2_kernel<<<1, 64, 0, stream>>>(bestv, besti, U);
    ctx_part_kernel<<<dim3(16, 16), 256, 0, stream>>>(qh, ql, kh, kl, x, U,
                                                      xbar_part, cm, cs);
    ctx_combine_kernel<<<16, 256, 0, stream>>>(xbar_part, cm, cs, Wv, bv, ctx);
    out_row_kernel<<<2, 256, 0, stream>>>(ctx, Wo, bo, rowbuf);
    out_bcast_kernel<<<2048, 256, 0, stream>>>(rowbuf, out);
}